// Round 1
// baseline (300.585 us; speedup 1.0000x reference)
//
#include <hip/hip_runtime.h>
#include <hip/hip_bf16.h>

typedef __attribute__((ext_vector_type(8))) short bf16x8;
typedef __attribute__((ext_vector_type(4))) float f32x4;
typedef __attribute__((ext_vector_type(4))) unsigned short us4;

__device__ __forceinline__ unsigned short f2bf(float f) {
    union { float f; unsigned u; } c; c.f = f;
    unsigned u = c.u;
    u += 0x7fffu + ((u >> 16) & 1u);   // RNE (no NaNs in this problem)
    return (unsigned short)(u >> 16);
}

// ---------------- Kernel 1: W -> WbT (bf16, transposed, [384][1024]) -------
__global__ __launch_bounds__(256) void wconv_kernel(
        const float* __restrict__ Wk, const float* __restrict__ Wq,
        const float* __restrict__ Wv, unsigned short* __restrict__ WbT) {
    int idx = blockIdx.x * 256 + threadIdx.x;     // 384*1024 total
    int n = idx >> 10, kk = idx & 1023;
    const float* W = (n < 128) ? Wk : (n < 256) ? Wq : Wv;
    int col = n & 127;
    WbT[idx] = f2bf(W[kk * 128 + col]);
}

// ---------------- Kernel 2: QKV projection GEMM ----------------------------
// C[16384 x 384] = x[16384 x 1024] * W[1024 x 384]; writes k,q row-major bf16
// and v transposed (vT[b][d][t]) bf16.
__global__ __launch_bounds__(256) void qkv_gemm_kernel(
        const float* __restrict__ x, const unsigned short* __restrict__ WbT,
        unsigned short* __restrict__ kw, unsigned short* __restrict__ qw,
        unsigned short* __restrict__ vTw) {
    __shared__ __align__(16) unsigned short Al[128 * 32];
    __shared__ __align__(16) unsigned short Bl[128 * 32];
    const int tid = threadIdx.x;
    const int m0 = blockIdx.x * 128;
    const int nt = blockIdx.y;                    // 0=key 1=query 2=value
    const int w = tid >> 6, l = tid & 63;
    const int wm = w >> 1, wn = w & 1;
    const int l15 = l & 15, lh = l >> 4;

    f32x4 acc[4][4] = {};

    for (int k0 = 0; k0 < 1024; k0 += 32) {
        __syncthreads();                           // protect prev-iter readers
        // stage A (fp32 -> bf16), tile [128][32]
        {
            int c8 = (tid & 3) * 8;
            for (int it = 0; it < 2; ++it) {
                int r = (tid >> 2) + it * 64;
                const float* src = &x[(size_t)(m0 + r) * 1024 + k0 + c8];
                float4 v0 = *(const float4*)src;
                float4 v1 = *(const float4*)(src + 4);
                union { unsigned short u[8]; bf16x8 v; } pk;
                pk.u[0] = f2bf(v0.x); pk.u[1] = f2bf(v0.y);
                pk.u[2] = f2bf(v0.z); pk.u[3] = f2bf(v0.w);
                pk.u[4] = f2bf(v1.x); pk.u[5] = f2bf(v1.y);
                pk.u[6] = f2bf(v1.z); pk.u[7] = f2bf(v1.w);
                *(bf16x8*)&Al[r * 32 + c8] = pk.v;
            }
        }
        // stage B (already bf16), tile [128][32] from WbT[nt*128 .. ][k0..]
        for (int it = 0; it < 2; ++it) {
            int r = (tid >> 2) + it * 64;
            int sl = tid & 3;
            bf16x8 v = *(const bf16x8*)&WbT[(size_t)(nt * 128 + r) * 1024 + k0 + sl * 8];
            *(bf16x8*)&Bl[r * 32 + sl * 8] = v;
        }
        __syncthreads();

        bf16x8 a[4], bb[4];
        for (int mi = 0; mi < 4; ++mi)
            a[mi] = *(bf16x8*)&Al[(wm * 64 + mi * 16 + l15) * 32 + lh * 8];
        for (int ni = 0; ni < 4; ++ni)
            bb[ni] = *(bf16x8*)&Bl[(wn * 64 + ni * 16 + l15) * 32 + lh * 8];
        for (int mi = 0; mi < 4; ++mi)
            for (int ni = 0; ni < 4; ++ni)
                acc[mi][ni] = __builtin_amdgcn_mfma_f32_16x16x32_bf16(
                        a[mi], bb[ni], acc[mi][ni], 0, 0, 0);
    }

    // epilogue: C/D layout col = l&15, row = (l>>4)*4 + i  (m89-verified)
    if (nt < 2) {
        unsigned short* dst = (nt == 0) ? kw : qw;
        for (int mi = 0; mi < 4; ++mi)
            for (int ni = 0; ni < 4; ++ni) {
                int col = wn * 64 + ni * 16 + l15;
                for (int i = 0; i < 4; ++i) {
                    int row = m0 + wm * 64 + mi * 16 + lh * 4 + i;
                    dst[(size_t)row * 128 + col] = f2bf(acc[mi][ni][i]);
                }
            }
    } else {
        // value: write transposed vT[b][d][t], pack 4 consecutive t as 8B
        for (int mi = 0; mi < 4; ++mi)
            for (int ni = 0; ni < 4; ++ni) {
                int col = wn * 64 + ni * 16 + l15;          // d
                int trow0 = m0 + wm * 64 + mi * 16 + lh * 4;
                int b = trow0 >> 12, t0 = trow0 & 4095;
                union { unsigned short u[4]; us4 v; } pk;
                for (int i = 0; i < 4; ++i) pk.u[i] = f2bf(acc[mi][ni][i]);
                *(us4*)&vTw[((size_t)(b * 128 + col)) * 4096 + t0] = pk.v;
            }
    }
}

// ---------------- Kernel 3: flash attention --------------------------------
// grid (64 qt, 4 b), 256 threads = 4 waves, each wave owns 16 q-rows.
__global__ __launch_bounds__(256) void attn_kernel(
        const unsigned short* __restrict__ kw, const unsigned short* __restrict__ qw,
        const unsigned short* __restrict__ vTw, float* __restrict__ out) {
    __shared__ __align__(16) unsigned short Kl[64 * 128];   // [kv row][d], swizzled
    __shared__ __align__(16) unsigned short Vl[128 * 64];   // [d][kv], swizzled
    __shared__ __align__(16) unsigned short Pl[4][16 * 72]; // per-wave P, padded

    const int tid = threadIdx.x;
    const int qt = blockIdx.x, b = blockIdx.y;
    const int w = tid >> 6, l = tid & 63;
    const int l15 = l & 15, lh = l >> 4;

    // Q fragments in registers: A[row=l15][k=lh*8+j + c*32]
    bf16x8 qa[4];
    {
        size_t grow = (size_t)b * 4096 + qt * 64 + w * 16 + l15;
        for (int c = 0; c < 4; ++c)
            qa[c] = *(const bf16x8*)&qw[grow * 128 + c * 32 + lh * 8];
    }

    f32x4 o[8] = {};
    float m_[4], ls[4];
    for (int i = 0; i < 4; ++i) { m_[i] = -INFINITY; ls[i] = 0.f; }

    for (int kt = 0; kt <= qt; ++kt) {
        const int kv0 = kt * 64;
        __syncthreads();                            // prev-iter readers done
        // stage K tile [64][128], XOR-swizzled rows
        for (int it = 0; it < 4; ++it) {
            int r = it * 16 + (tid >> 4);
            int sl = tid & 15;
            bf16x8 v = *(const bf16x8*)&kw[((size_t)(b * 4096 + kv0 + r)) * 128 + sl * 8];
            int byteoff = r * 256 + ((sl * 16) ^ ((r & 7) << 4));
            *(bf16x8*)((char*)Kl + byteoff) = v;
        }
        // stage vT tile [128][64], XOR-swizzled rows
        for (int it = 0; it < 4; ++it) {
            int d = it * 32 + (tid >> 3);
            int sl = tid & 7;
            bf16x8 v = *(const bf16x8*)&vTw[((size_t)(b * 128 + d)) * 4096 + kv0 + sl * 8];
            int byteoff = d * 128 + ((sl * 16) ^ ((d & 7) << 4));
            *(bf16x8*)((char*)Vl + byteoff) = v;
        }
        __syncthreads();

        // S = Q K^T  (B-frag: B[k=d][n=kvrow] = K[kvrow][d])
        f32x4 s[4];
        for (int ni = 0; ni < 4; ++ni) {
            s[ni] = (f32x4){0.f, 0.f, 0.f, 0.f};
            int kr = ni * 16 + l15;
            int sw = (kr & 7) << 4;
            for (int c = 0; c < 4; ++c) {
                bf16x8 bk = *(bf16x8*)((char*)Kl + kr * 256 + ((lh * 16 + c * 64) ^ sw));
                s[ni] = __builtin_amdgcn_mfma_f32_16x16x32_bf16(qa[c], bk, s[ni], 0, 0, 0);
            }
        }
        // scale + causal mask (diag tile only)
        const bool diag = (kt == qt);
        for (int ni = 0; ni < 4; ++ni)
            for (int i = 0; i < 4; ++i) {
                float v = s[ni][i] * 0.03125f;      // C^-0.5 = 1024^-0.5
                bool masked = diag && (ni * 16 + l15 > w * 16 + lh * 4 + i);
                s[ni][i] = masked ? -INFINITY : v;
            }
        // online softmax, rows live on 16-lane groups (row = lh*4+i)
        float sc[4];
        for (int i = 0; i < 4; ++i) {
            float mx = fmaxf(fmaxf(s[0][i], s[1][i]), fmaxf(s[2][i], s[3][i]));
            for (int msk = 1; msk < 16; msk <<= 1) mx = fmaxf(mx, __shfl_xor(mx, msk));
            float mn = fmaxf(m_[i], mx);
            float e = __expf(m_[i] - mn);
            m_[i] = mn;
            float rs = 0.f;
            for (int ni = 0; ni < 4; ++ni) {
                float p = __expf(s[ni][i] - mn);
                s[ni][i] = p; rs += p;
            }
            for (int msk = 1; msk < 16; msk <<= 1) rs += __shfl_xor(rs, msk);
            ls[i] = ls[i] * e + rs;
            sc[i] = e;
        }
        for (int nd = 0; nd < 8; ++nd) {
            f32x4 t = o[nd];
            t[0] *= sc[0]; t[1] *= sc[1]; t[2] *= sc[2]; t[3] *= sc[3];
            o[nd] = t;
        }
        // P (C-layout) -> LDS (row-major, +8 pad), wave-local
        for (int ni = 0; ni < 4; ++ni)
            for (int i = 0; i < 4; ++i)
                Pl[w][(lh * 4 + i) * 72 + ni * 16 + l15] = f2bf(s[ni][i]);
        // PV: A = P[q][kv] (k-contiguous), B[k=kv][n=d] = vT[d][kv]
        bf16x8 pa[2];
        for (int kc = 0; kc < 2; ++kc)
            pa[kc] = *(bf16x8*)&Pl[w][l15 * 72 + kc * 32 + lh * 8];
        for (int nd = 0; nd < 8; ++nd) {
            int dr = nd * 16 + l15;
            int sw = (dr & 7) << 4;
            for (int kc = 0; kc < 2; ++kc) {
                bf16x8 bv = *(bf16x8*)((char*)Vl + dr * 128 + ((lh * 16 + kc * 64) ^ sw));
                o[nd] = __builtin_amdgcn_mfma_f32_16x16x32_bf16(pa[kc], bv, o[nd], 0, 0, 0);
            }
        }
    }

    // epilogue: out fp32 [b][t][d]
    for (int nd = 0; nd < 8; ++nd)
        for (int i = 0; i < 4; ++i) {
            size_t row = (size_t)b * 4096 + qt * 64 + w * 16 + lh * 4 + i;
            out[row * 128 + nd * 16 + l15] = o[nd][i] / ls[i];
        }
}

// ---------------------------------------------------------------------------
extern "C" void kernel_launch(void* const* d_in, const int* in_sizes, int n_in,
                              void* d_out, int out_size, void* d_ws, size_t ws_size,
                              hipStream_t stream) {
    const float* x  = (const float*)d_in[0];
    const float* Wk = (const float*)d_in[1];
    const float* Wq = (const float*)d_in[2];
    const float* Wv = (const float*)d_in[3];
    float* out = (float*)d_out;

    // ws layout (bytes): WbT 786432 | k 4194304 | q 4194304 | vT 4194304
    char* ws = (char*)d_ws;
    unsigned short* WbT = (unsigned short*)(ws);
    unsigned short* kw  = (unsigned short*)(ws + 786432);
    unsigned short* qw  = (unsigned short*)(ws + 786432 + 4194304);
    unsigned short* vTw = (unsigned short*)(ws + 786432 + 2 * 4194304);

    wconv_kernel<<<1536, 256, 0, stream>>>(Wk, Wq, Wv, WbT);
    qkv_gemm_kernel<<<dim3(128, 3), 256, 0, stream>>>(x, WbT, kw, qw, vTw);
    attn_kernel<<<dim3(64, 4), 256, 0, stream>>>(kw, qw, vTw, out);
}

// Round 2
// 133.342 us; speedup vs baseline: 2.2542x; 2.2542x over previous
//
#include <hip/hip_runtime.h>
#include <hip/hip_bf16.h>

typedef __attribute__((ext_vector_type(8))) short bf16x8;
typedef __attribute__((ext_vector_type(4))) float f32x4;
typedef __attribute__((ext_vector_type(4))) unsigned short us4;

__device__ __forceinline__ unsigned short f2bf(float f) {
    union { float f; unsigned u; } c; c.f = f;
    unsigned u = c.u;
    u += 0x7fffu + ((u >> 16) & 1u);   // RNE (no NaNs in this problem)
    return (unsigned short)(u >> 16);
}
__device__ __forceinline__ float bf2f(unsigned short h) {
    union { unsigned u; float f; } c; c.u = ((unsigned)h) << 16;
    return c.f;
}

// ---------------- Kernel 1: W -> WbT (bf16, transposed, [384][1024]) -------
__global__ __launch_bounds__(256) void wconv_kernel(
        const float* __restrict__ Wk, const float* __restrict__ Wq,
        const float* __restrict__ Wv, unsigned short* __restrict__ WbT) {
    int idx = blockIdx.x * 256 + threadIdx.x;     // 384*1024 total
    int n = idx >> 10, kk = idx & 1023;
    const float* W = (n < 128) ? Wk : (n < 256) ? Wq : Wv;
    int col = n & 127;
    WbT[idx] = f2bf(W[kk * 128 + col]);
}

// ---------------- Kernel 2: QKV projection GEMM ----------------------------
__global__ __launch_bounds__(256) void qkv_gemm_kernel(
        const float* __restrict__ x, const unsigned short* __restrict__ WbT,
        unsigned short* __restrict__ kw, unsigned short* __restrict__ qw,
        unsigned short* __restrict__ vTw) {
    __shared__ __align__(16) unsigned short Al[128 * 32];
    __shared__ __align__(16) unsigned short Bl[128 * 32];
    const int tid = threadIdx.x;
    const int m0 = blockIdx.x * 128;
    const int nt = blockIdx.y;                    // 0=key 1=query 2=value
    const int w = tid >> 6, l = tid & 63;
    const int wm = w >> 1, wn = w & 1;
    const int l15 = l & 15, lh = l >> 4;

    f32x4 acc[4][4] = {};

    for (int k0 = 0; k0 < 1024; k0 += 32) {
        __syncthreads();
        {
            int c8 = (tid & 3) * 8;
            for (int it = 0; it < 2; ++it) {
                int r = (tid >> 2) + it * 64;
                const float* src = &x[(size_t)(m0 + r) * 1024 + k0 + c8];
                float4 v0 = *(const float4*)src;
                float4 v1 = *(const float4*)(src + 4);
                union { unsigned short u[8]; bf16x8 v; } pk;
                pk.u[0] = f2bf(v0.x); pk.u[1] = f2bf(v0.y);
                pk.u[2] = f2bf(v0.z); pk.u[3] = f2bf(v0.w);
                pk.u[4] = f2bf(v1.x); pk.u[5] = f2bf(v1.y);
                pk.u[6] = f2bf(v1.z); pk.u[7] = f2bf(v1.w);
                *(bf16x8*)&Al[r * 32 + c8] = pk.v;
            }
        }
        for (int it = 0; it < 2; ++it) {
            int r = (tid >> 2) + it * 64;
            int sl = tid & 3;
            bf16x8 v = *(const bf16x8*)&WbT[(size_t)(nt * 128 + r) * 1024 + k0 + sl * 8];
            *(bf16x8*)&Bl[r * 32 + sl * 8] = v;
        }
        __syncthreads();

        bf16x8 a[4], bb[4];
        for (int mi = 0; mi < 4; ++mi)
            a[mi] = *(bf16x8*)&Al[(wm * 64 + mi * 16 + l15) * 32 + lh * 8];
        for (int ni = 0; ni < 4; ++ni)
            bb[ni] = *(bf16x8*)&Bl[(wn * 64 + ni * 16 + l15) * 32 + lh * 8];
        for (int mi = 0; mi < 4; ++mi)
            for (int ni = 0; ni < 4; ++ni)
                acc[mi][ni] = __builtin_amdgcn_mfma_f32_16x16x32_bf16(
                        a[mi], bb[ni], acc[mi][ni], 0, 0, 0);
    }

    if (nt < 2) {
        unsigned short* dst = (nt == 0) ? kw : qw;
        for (int mi = 0; mi < 4; ++mi)
            for (int ni = 0; ni < 4; ++ni) {
                int col = wn * 64 + ni * 16 + l15;
                for (int i = 0; i < 4; ++i) {
                    int row = m0 + wm * 64 + mi * 16 + lh * 4 + i;
                    dst[(size_t)row * 128 + col] = f2bf(acc[mi][ni][i]);
                }
            }
    } else {
        for (int mi = 0; mi < 4; ++mi)
            for (int ni = 0; ni < 4; ++ni) {
                int col = wn * 64 + ni * 16 + l15;          // d
                int trow0 = m0 + wm * 64 + mi * 16 + lh * 4;
                int b = trow0 >> 12, t0 = trow0 & 4095;
                union { unsigned short u[4]; us4 v; } pk;
                for (int i = 0; i < 4; ++i) pk.u[i] = f2bf(acc[mi][ni][i]);
                *(us4*)&vTw[((size_t)(b * 128 + col)) * 4096 + t0] = pk.v;
            }
    }
}

// ---------------- Kernel 3: split-KV flash attention -----------------------
// Per batch: 160 chunk-blocks. Chunk = (qt, c): q-tile qt (64 rows), kv tiles
// [16c, min(16c+16, qt+1)). Writes unnormalized partial O (bf16) + m,l (f32).
__global__ __launch_bounds__(256) void attn_kernel(
        const unsigned short* __restrict__ kw, const unsigned short* __restrict__ qw,
        const unsigned short* __restrict__ vTw,
        unsigned short* __restrict__ pO, float* __restrict__ pML) {
    __shared__ __align__(16) unsigned short Kl[64 * 128];   // [kv row][d], swizzled
    __shared__ __align__(16) unsigned short Vl[128 * 64];   // [d][kv], swizzled
    __shared__ __align__(16) unsigned short Pl[4][16 * 72]; // per-wave P, padded

    const int tid = threadIdx.x;
    const int b = blockIdx.y;
    const int cid = 159 - blockIdx.x;             // longest chunks first
    int qt, c;
    if (cid < 16)      { qt = cid;                 c = 0; }
    else if (cid < 48) { qt = 16 + (cid - 16) / 2; c = (cid - 16) % 2; }
    else if (cid < 96) { qt = 32 + (cid - 48) / 3; c = (cid - 48) % 3; }
    else               { qt = 48 + (cid - 96) / 4; c = (cid - 96) % 4; }
    const int kt0 = c * 16;
    const int kt1 = min(kt0 + 16, qt + 1);

    const int w = tid >> 6, l = tid & 63;
    const int l15 = l & 15, lh = l >> 4;

    bf16x8 qa[4];
    {
        size_t grow = (size_t)b * 4096 + qt * 64 + w * 16 + l15;
        for (int cc = 0; cc < 4; ++cc)
            qa[cc] = *(const bf16x8*)&qw[grow * 128 + cc * 32 + lh * 8];
    }

    f32x4 o[8] = {};
    float m_[4], ls[4];
    for (int i = 0; i < 4; ++i) { m_[i] = -INFINITY; ls[i] = 0.f; }

    for (int kt = kt0; kt < kt1; ++kt) {
        const int kv0 = kt * 64;
        __syncthreads();
        for (int it = 0; it < 4; ++it) {
            int r = it * 16 + (tid >> 4);
            int sl = tid & 15;
            bf16x8 v = *(const bf16x8*)&kw[((size_t)(b * 4096 + kv0 + r)) * 128 + sl * 8];
            int byteoff = r * 256 + ((sl * 16) ^ ((r & 7) << 4));
            *(bf16x8*)((char*)Kl + byteoff) = v;
        }
        for (int it = 0; it < 4; ++it) {
            int d = it * 32 + (tid >> 3);
            int sl = tid & 7;
            bf16x8 v = *(const bf16x8*)&vTw[((size_t)(b * 128 + d)) * 4096 + kv0 + sl * 8];
            int byteoff = d * 128 + ((sl * 16) ^ ((d & 7) << 4));
            *(bf16x8*)((char*)Vl + byteoff) = v;
        }
        __syncthreads();

        f32x4 s[4];
        for (int ni = 0; ni < 4; ++ni) {
            s[ni] = (f32x4){0.f, 0.f, 0.f, 0.f};
            int kr = ni * 16 + l15;
            int sw = (kr & 7) << 4;
            for (int cc = 0; cc < 4; ++cc) {
                bf16x8 bk = *(bf16x8*)((char*)Kl + kr * 256 + ((lh * 16 + cc * 64) ^ sw));
                s[ni] = __builtin_amdgcn_mfma_f32_16x16x32_bf16(qa[cc], bk, s[ni], 0, 0, 0);
            }
        }
        const bool diag = (kt == qt);
        for (int ni = 0; ni < 4; ++ni)
            for (int i = 0; i < 4; ++i) {
                float v = s[ni][i] * 0.03125f;      // C^-0.5
                bool masked = diag && (ni * 16 + l15 > w * 16 + lh * 4 + i);
                s[ni][i] = masked ? -INFINITY : v;
            }
        float sc[4];
        for (int i = 0; i < 4; ++i) {
            float mx = fmaxf(fmaxf(s[0][i], s[1][i]), fmaxf(s[2][i], s[3][i]));
            for (int msk = 1; msk < 16; msk <<= 1) mx = fmaxf(mx, __shfl_xor(mx, msk));
            float mn = fmaxf(m_[i], mx);
            float e = __expf(m_[i] - mn);
            m_[i] = mn;
            float rs = 0.f;
            for (int ni = 0; ni < 4; ++ni) {
                float p = __expf(s[ni][i] - mn);
                s[ni][i] = p; rs += p;
            }
            for (int msk = 1; msk < 16; msk <<= 1) rs += __shfl_xor(rs, msk);
            ls[i] = ls[i] * e + rs;
            sc[i] = e;
        }
        for (int nd = 0; nd < 8; ++nd) {
            f32x4 t = o[nd];
            t[0] *= sc[0]; t[1] *= sc[1]; t[2] *= sc[2]; t[3] *= sc[3];
            o[nd] = t;
        }
        for (int ni = 0; ni < 4; ++ni)
            for (int i = 0; i < 4; ++i)
                Pl[w][(lh * 4 + i) * 72 + ni * 16 + l15] = f2bf(s[ni][i]);
        bf16x8 pa[2];
        for (int kc = 0; kc < 2; ++kc)
            pa[kc] = *(bf16x8*)&Pl[w][l15 * 72 + kc * 32 + lh * 8];
        for (int nd = 0; nd < 8; ++nd) {
            int dr = nd * 16 + l15;
            int sw = (dr & 7) << 4;
            for (int kc = 0; kc < 2; ++kc) {
                bf16x8 bv = *(bf16x8*)((char*)Vl + dr * 128 + ((lh * 16 + kc * 64) ^ sw));
                o[nd] = __builtin_amdgcn_mfma_f32_16x16x32_bf16(pa[kc], bv, o[nd], 0, 0, 0);
            }
        }
    }

    // epilogue: unnormalized partial O (bf16) + m,l (f32) into slot
    const int slot = (b * 64 + qt) * 4 + c;
    unsigned short* po = pO + (size_t)slot * 8192;
    for (int nd = 0; nd < 8; ++nd)
        for (int i = 0; i < 4; ++i)
            po[(w * 16 + lh * 4 + i) * 128 + nd * 16 + l15] = f2bf(o[nd][i]);
    if (l15 == 0) {
        float* pml = pML + (size_t)slot * 128;
        for (int i = 0; i < 4; ++i) {
            int row = w * 16 + lh * 4 + i;
            pml[row * 2]     = m_[i];
            pml[row * 2 + 1] = ls[i];
        }
    }
}

// ---------------- Kernel 4: combine partials -------------------------------
__global__ __launch_bounds__(256) void combine_kernel(
        const unsigned short* __restrict__ pO, const float* __restrict__ pML,
        float* __restrict__ out) {
    int idx = blockIdx.x * 256 + threadIdx.x;     // B*T*128 = 2097152
    int row = idx >> 7, d = idx & 127;
    int b = row >> 12, t = row & 4095;
    int qt = t >> 6, rowin = t & 63;
    int nch = (qt >> 4) + 1;                      // ceil((qt+1)/16)
    int slotbase = (b * 64 + qt) * 4;

    float mv[4], lv[4];
    float M = -INFINITY;
    for (int cc = 0; cc < nch; ++cc) {
        mv[cc] = pML[(size_t)(slotbase + cc) * 128 + rowin * 2];
        lv[cc] = pML[(size_t)(slotbase + cc) * 128 + rowin * 2 + 1];
        M = fmaxf(M, mv[cc]);
    }
    float num = 0.f, den = 0.f;
    for (int cc = 0; cc < nch; ++cc) {
        float wgt = __expf(mv[cc] - M);
        num += wgt * bf2f(pO[(size_t)(slotbase + cc) * 8192 + rowin * 128 + d]);
        den += wgt * lv[cc];
    }
    out[idx] = num / den;
}

// ---------------------------------------------------------------------------
extern "C" void kernel_launch(void* const* d_in, const int* in_sizes, int n_in,
                              void* d_out, int out_size, void* d_ws, size_t ws_size,
                              hipStream_t stream) {
    const float* x  = (const float*)d_in[0];
    const float* Wk = (const float*)d_in[1];
    const float* Wq = (const float*)d_in[2];
    const float* Wv = (const float*)d_in[3];
    float* out = (float*)d_out;

    // ws layout (bytes):
    //   WbT 786432 | k 4194304 | q 4194304 | vT 4194304 | pO 16777216 | pML 524288
    char* ws = (char*)d_ws;
    unsigned short* WbT = (unsigned short*)(ws);
    unsigned short* kw  = (unsigned short*)(ws + 786432);
    unsigned short* qw  = (unsigned short*)(ws + 786432 + 4194304);
    unsigned short* vTw = (unsigned short*)(ws + 786432 + 2 * 4194304);
    unsigned short* pO  = (unsigned short*)(ws + 786432 + 3 * 4194304);
    float*          pML = (float*)(ws + 786432 + 3 * 4194304 + 16777216);

    wconv_kernel<<<1536, 256, 0, stream>>>(Wk, Wq, Wv, WbT);
    qkv_gemm_kernel<<<dim3(128, 3), 256, 0, stream>>>(x, WbT, kw, qw, vTw);
    attn_kernel<<<dim3(160, 4), 256, 0, stream>>>(kw, qw, vTw, pO, pML);
    combine_kernel<<<8192, 256, 0, stream>>>(pO, pML, out);
}